// Round 4
// baseline (522.055 us; speedup 1.0000x reference)
//
#include <hip/hip_runtime.h>

// ---------------------------------------------------------------------------
// AuxiliaryYFixed: loc = z_ins @ W.T + b  ([N,128] -> [N]);
//                  M[b] = max over bag (sorted bag_idx), empty bags -> 0.0
// Output layout: d_out = [ M (B floats) | loc (N floats) ]
// Memory-bound: ~1.04 GB traffic. R1: 194.5 us. R3: 174.5 us (5.96 TB/s).
// R4: full-tile fast path (N%64==0 -> unconditional loads) + finalize folded
//     into main via last-block-done (drops one launch). Target ~168 us.
// ---------------------------------------------------------------------------

typedef float vfloat4 __attribute__((ext_vector_type(4)));

__device__ __forceinline__ unsigned int flip_f32(float f) {
    unsigned int u = __float_as_uint(f);
    return u ^ ((unsigned int)((int)u >> 31) | 0x80000000u);
}
__device__ __forceinline__ float unflip_f32(unsigned int u) {
    unsigned int b = (u & 0x80000000u) ? (u ^ 0x80000000u) : ~u;
    return __uint_as_float(b);
}

__global__ __launch_bounds__(256, 4) void linseg_main_kernel(
    const float* __restrict__ z,      // [N,128]
    const int*   __restrict__ bag,    // [N] (sorted, values in [0,B))
    const float* __restrict__ W,      // [128]
    const float* __restrict__ bptr,   // [1]
    float*       __restrict__ loc,    // [N]  (d_out + B)
    float*       __restrict__ M,      // [B]  (d_out)
    unsigned int* __restrict__ Mu,    // [B]  workspace keys, pre-zeroed
    unsigned int* __restrict__ done,  // [1]  workspace counter, pre-zeroed
    int N, int B)
{
    __shared__ float smem[4][64];     // per-wave row-result transpose buffer
    __shared__ bool  islast;
    const int lane = threadIdx.x & 63;
    const int wid  = threadIdx.x >> 6;
    const int half = lane >> 5;       // which row of a pair this lane loads
    const int q    = lane & 31;       // float4 slot within the 128-wide row
    const vfloat4 w4 = reinterpret_cast<const vfloat4*>(W)[q];
    const float bias = bptr[0];

    const int ntiles = (N + 63) >> 6;                       // 64 rows per tile
    const int gwaves = (int)((gridDim.x * blockDim.x) >> 6);
    const int gw0    = (int)((blockIdx.x * blockDim.x + threadIdx.x) >> 6);

    for (int t = gw0; t < ntiles; t += gwaves) {
        const int base = t << 6;
        if (base + 64 <= N) {
            // ---- full tile: unconditional loads, 4 rows/iter, 2 chains ----
            #pragma unroll 4
            for (int i = 0; i < 16; ++i) {
                const int rowA = base + 4 * i + half;
                const int rowB = rowA + 2;
                vfloat4 vA = __builtin_nontemporal_load(
                    reinterpret_cast<const vfloat4*>(z + (size_t)rowA * 128) + q);
                vfloat4 vB = __builtin_nontemporal_load(
                    reinterpret_cast<const vfloat4*>(z + (size_t)rowB * 128) + q);
                float sA = vA.x * w4.x + vA.y * w4.y + vA.z * w4.z + vA.w * w4.w;
                float sB = vB.x * w4.x + vB.y * w4.y + vB.z * w4.z + vB.w * w4.w;
                sA += __shfl_xor(sA, 16);  sB += __shfl_xor(sB, 16);
                sA += __shfl_xor(sA, 8);   sB += __shfl_xor(sB, 8);
                sA += __shfl_xor(sA, 4);   sB += __shfl_xor(sB, 4);
                sA += __shfl_xor(sA, 2);   sB += __shfl_xor(sB, 2);
                sA += __shfl_xor(sA, 1);   sB += __shfl_xor(sB, 1);
                if (q == 2 * i)     smem[wid][4 * i + half]     = sA + bias;
                if (q == 2 * i + 1) smem[wid][4 * i + 2 + half] = sB + bias;
            }
        } else {
            // ---- ragged tail tile: guarded loads ----
            #pragma unroll 4
            for (int i = 0; i < 16; ++i) {
                const int rowA = base + 4 * i + half;
                const int rowB = rowA + 2;
                vfloat4 vA = (vfloat4)0.0f;
                vfloat4 vB = (vfloat4)0.0f;
                if (rowA < N)
                    vA = __builtin_nontemporal_load(
                        reinterpret_cast<const vfloat4*>(z + (size_t)rowA * 128) + q);
                if (rowB < N)
                    vB = __builtin_nontemporal_load(
                        reinterpret_cast<const vfloat4*>(z + (size_t)rowB * 128) + q);
                float sA = vA.x * w4.x + vA.y * w4.y + vA.z * w4.z + vA.w * w4.w;
                float sB = vB.x * w4.x + vB.y * w4.y + vB.z * w4.z + vB.w * w4.w;
                sA += __shfl_xor(sA, 16);  sB += __shfl_xor(sB, 16);
                sA += __shfl_xor(sA, 8);   sB += __shfl_xor(sB, 8);
                sA += __shfl_xor(sA, 4);   sB += __shfl_xor(sB, 4);
                sA += __shfl_xor(sA, 2);   sB += __shfl_xor(sB, 2);
                sA += __shfl_xor(sA, 1);   sB += __shfl_xor(sB, 1);
                if (q == 2 * i)     smem[wid][4 * i + half]     = sA + bias;
                if (q == 2 * i + 1) smem[wid][4 * i + 2 + half] = sB + bias;
            }
        }
        // --- transpose: lane <- row base+lane (intra-wave LDS, no barrier) ---
        const int row = base + lane;
        const float val = smem[wid][lane];
        if (row < N) __builtin_nontemporal_store(val, loc + row);

        // --- segmented max over sorted bags within the 64-row window ---
        const int mybag = (row < N) ? __builtin_nontemporal_load(bag + row) : -1;
        float v = val;
        #pragma unroll
        for (int s = 1; s < 64; s <<= 1) {
            const float ov = __shfl_up(v, s);
            const int   ob = __shfl_up(mybag, s);
            if (lane >= s && ob == mybag) v = fmaxf(v, ov);
        }
        const int nxt = __shfl_down(mybag, 1);
        const bool tail = (lane == 63) || (nxt != mybag);
        if (tail && mybag >= 0)
            atomicMax(&Mu[mybag], flip_f32(v));               // ~1-2 per tile
    }

    // --- last-block finalize: decode Mu -> M (saves a kernel launch) ---
    __threadfence();                       // release our Mu atomics device-wide
    __syncthreads();
    if (threadIdx.x == 0)
        islast = (atomicAdd(done, 1u) == gridDim.x - 1);
    __syncthreads();
    if (islast) {
        __threadfence();                   // acquire all blocks' Mu updates
        for (int i = threadIdx.x; i < B; i += blockDim.x) {
            const unsigned int u = __hip_atomic_load(
                &Mu[i], __ATOMIC_RELAXED, __HIP_MEMORY_SCOPE_AGENT);
            M[i] = (u == 0u) ? 0.0f : unflip_f32(u);
        }
    }
}

extern "C" void kernel_launch(void* const* d_in, const int* in_sizes, int n_in,
                              void* d_out, int out_size, void* d_ws, size_t ws_size,
                              hipStream_t stream) {
    const float* z    = (const float*)d_in[0];
    const int*   bag  = (const int*)  d_in[1];
    const float* W    = (const float*)d_in[2];
    const float* bptr = (const float*)d_in[3];

    const int N = in_sizes[1];            // bag_idx element count
    const int B = out_size - N;           // M is the first output chunk

    float* M_out   = (float*)d_out;       // [B]
    float* loc_out = (float*)d_out + B;   // [N]
    unsigned int* Mu   = (unsigned int*)d_ws;
    unsigned int* done = Mu + B;          // [1] completion counter

    // zero per-bag keys + done counter (graph-capturable async memset)
    (void)hipMemsetAsync(Mu, 0, (size_t)(B + 1) * sizeof(unsigned int), stream);

    const int ntiles = (N + 63) >> 6;
    int blocks = (ntiles + 3) / 4;        // 4 waves per 256-thread block
    if (blocks > 2048) blocks = 2048;     // grid-stride the rest
    if (blocks < 1) blocks = 1;

    linseg_main_kernel<<<blocks, 256, 0, stream>>>(z, bag, W, bptr,
                                                   loc_out, M_out, Mu, done,
                                                   N, B);
}

// Round 5
// 174.604 us; speedup vs baseline: 2.9899x; 2.9899x over previous
//
#include <hip/hip_runtime.h>

// ---------------------------------------------------------------------------
// AuxiliaryYFixed: loc = z_ins @ W.T + b  ([N,128] -> [N]);
//                  M[b] = max over bag (sorted bag_idx), empty bags -> 0.0
// Output layout: d_out = [ M (B floats) | loc (N floats) ]
// Memory-bound: ~1.04 GB traffic. R1: 194.5. R3: 174.5 us (5.96 TB/s eff).
// R4 FAILED (522 us): per-block __threadfence() = device-scope release =
//   per-XCD L2 writeback/invalidate x2048 blocks + serialized done-counter
//   atomics. Lesson: cross-XCD visibility via kernel boundary, not fences.
// R5: R3 structure (two kernels, no fences) + full-tile fast path only.
// ---------------------------------------------------------------------------

typedef float vfloat4 __attribute__((ext_vector_type(4)));

__device__ __forceinline__ unsigned int flip_f32(float f) {
    unsigned int u = __float_as_uint(f);
    return u ^ ((unsigned int)((int)u >> 31) | 0x80000000u);
}
__device__ __forceinline__ float unflip_f32(unsigned int u) {
    unsigned int b = (u & 0x80000000u) ? (u ^ 0x80000000u) : ~u;
    return __uint_as_float(b);
}

__global__ __launch_bounds__(256, 4) void linseg_main_kernel(
    const float* __restrict__ z,      // [N,128]
    const int*   __restrict__ bag,    // [N] (sorted, values in [0,B))
    const float* __restrict__ W,      // [128]
    const float* __restrict__ bptr,   // [1]
    float*       __restrict__ loc,    // [N]  (d_out + B)
    unsigned int* __restrict__ Mu,    // [B]  workspace keys, pre-zeroed
    int N)
{
    __shared__ float smem[4][64];     // per-wave row-result transpose buffer
    const int lane = threadIdx.x & 63;
    const int wid  = threadIdx.x >> 6;
    const int half = lane >> 5;       // which row of a pair this lane loads
    const int q    = lane & 31;       // float4 slot within the 128-wide row
    const vfloat4 w4 = reinterpret_cast<const vfloat4*>(W)[q];
    const float bias = bptr[0];

    const int ntiles = (N + 63) >> 6;                       // 64 rows per tile
    const int gwaves = (int)((gridDim.x * blockDim.x) >> 6);
    const int gw0    = (int)((blockIdx.x * blockDim.x + threadIdx.x) >> 6);

    for (int t = gw0; t < ntiles; t += gwaves) {
        const int base = t << 6;
        if (base + 64 <= N) {
            // ---- full tile: unconditional loads, 4 rows/iter, 2 chains ----
            #pragma unroll 4
            for (int i = 0; i < 16; ++i) {
                const int rowA = base + 4 * i + half;
                const int rowB = rowA + 2;
                vfloat4 vA = __builtin_nontemporal_load(
                    reinterpret_cast<const vfloat4*>(z + (size_t)rowA * 128) + q);
                vfloat4 vB = __builtin_nontemporal_load(
                    reinterpret_cast<const vfloat4*>(z + (size_t)rowB * 128) + q);
                float sA = vA.x * w4.x + vA.y * w4.y + vA.z * w4.z + vA.w * w4.w;
                float sB = vB.x * w4.x + vB.y * w4.y + vB.z * w4.z + vB.w * w4.w;
                sA += __shfl_xor(sA, 16);  sB += __shfl_xor(sB, 16);
                sA += __shfl_xor(sA, 8);   sB += __shfl_xor(sB, 8);
                sA += __shfl_xor(sA, 4);   sB += __shfl_xor(sB, 4);
                sA += __shfl_xor(sA, 2);   sB += __shfl_xor(sB, 2);
                sA += __shfl_xor(sA, 1);   sB += __shfl_xor(sB, 1);
                if (q == 2 * i)     smem[wid][4 * i + half]     = sA + bias;
                if (q == 2 * i + 1) smem[wid][4 * i + 2 + half] = sB + bias;
            }
        } else {
            // ---- ragged tail tile: guarded loads ----
            #pragma unroll 4
            for (int i = 0; i < 16; ++i) {
                const int rowA = base + 4 * i + half;
                const int rowB = rowA + 2;
                vfloat4 vA = (vfloat4)0.0f;
                vfloat4 vB = (vfloat4)0.0f;
                if (rowA < N)
                    vA = __builtin_nontemporal_load(
                        reinterpret_cast<const vfloat4*>(z + (size_t)rowA * 128) + q);
                if (rowB < N)
                    vB = __builtin_nontemporal_load(
                        reinterpret_cast<const vfloat4*>(z + (size_t)rowB * 128) + q);
                float sA = vA.x * w4.x + vA.y * w4.y + vA.z * w4.z + vA.w * w4.w;
                float sB = vB.x * w4.x + vB.y * w4.y + vB.z * w4.z + vB.w * w4.w;
                sA += __shfl_xor(sA, 16);  sB += __shfl_xor(sB, 16);
                sA += __shfl_xor(sA, 8);   sB += __shfl_xor(sB, 8);
                sA += __shfl_xor(sA, 4);   sB += __shfl_xor(sB, 4);
                sA += __shfl_xor(sA, 2);   sB += __shfl_xor(sB, 2);
                sA += __shfl_xor(sA, 1);   sB += __shfl_xor(sB, 1);
                if (q == 2 * i)     smem[wid][4 * i + half]     = sA + bias;
                if (q == 2 * i + 1) smem[wid][4 * i + 2 + half] = sB + bias;
            }
        }
        // --- transpose: lane <- row base+lane (intra-wave LDS, no barrier) ---
        const int row = base + lane;
        const float val = smem[wid][lane];
        if (row < N) __builtin_nontemporal_store(val, loc + row);

        // --- segmented max over sorted bags within the 64-row window ---
        const int mybag = (row < N) ? __builtin_nontemporal_load(bag + row) : -1;
        float v = val;
        #pragma unroll
        for (int s = 1; s < 64; s <<= 1) {
            const float ov = __shfl_up(v, s);
            const int   ob = __shfl_up(mybag, s);
            if (lane >= s && ob == mybag) v = fmaxf(v, ov);
        }
        const int nxt = __shfl_down(mybag, 1);
        const bool tail = (lane == 63) || (nxt != mybag);
        if (tail && mybag >= 0)
            atomicMax(&Mu[mybag], flip_f32(v));               // ~1-2 per tile
    }
}

__global__ void linseg_finalize_kernel(const unsigned int* __restrict__ Mu,
                                       float* __restrict__ M, int B)
{
    const int i = blockIdx.x * blockDim.x + threadIdx.x;
    if (i < B) {
        const unsigned int u = Mu[i];
        M[i] = (u == 0u) ? 0.0f : unflip_f32(u);
    }
}

extern "C" void kernel_launch(void* const* d_in, const int* in_sizes, int n_in,
                              void* d_out, int out_size, void* d_ws, size_t ws_size,
                              hipStream_t stream) {
    const float* z    = (const float*)d_in[0];
    const int*   bag  = (const int*)  d_in[1];
    const float* W    = (const float*)d_in[2];
    const float* bptr = (const float*)d_in[3];

    const int N = in_sizes[1];            // bag_idx element count
    const int B = out_size - N;           // M is the first output chunk

    float* M_out   = (float*)d_out;       // [B]
    float* loc_out = (float*)d_out + B;   // [N]
    unsigned int* Mu = (unsigned int*)d_ws;

    // zero the per-bag key accumulator (graph-capturable async memset)
    (void)hipMemsetAsync(Mu, 0, (size_t)B * sizeof(unsigned int), stream);

    const int ntiles = (N + 63) >> 6;
    int blocks = (ntiles + 3) / 4;        // 4 waves per 256-thread block
    if (blocks > 2048) blocks = 2048;     // grid-stride the rest
    if (blocks < 1) blocks = 1;

    linseg_main_kernel<<<blocks, 256, 0, stream>>>(z, bag, W, bptr,
                                                   loc_out, Mu, N);
    linseg_finalize_kernel<<<(B + 255) / 256, 256, 0, stream>>>(Mu, M_out, B);
}